// Round 1
// baseline (1110.088 us; speedup 1.0000x reference)
//
#include <hip/hip_runtime.h>
#include <cstddef>

// TransitionDown: B=16 clouds, P=4096 pts, S=1024 fps samples, K=16 knn,
// IN_F=256, OUT_F=512.
// Pipeline:
//   L1 fused: blocks[0,16)   FPS per cloud (np-bitwise fp32, contract off),
//                            512 active thr (2 waves/SIMD), packed v2f math,
//                            64-bit DPP wave-argmax, 1 barrier/step.
//             blocks[16,1040) MLP GEMM fp32 -> h bf16 (hidden under FPS)
//             blocks[1040,2064) xx[i] = ||features_i||^2
//   L2: BN partial sums over h   L3: BN finalize -> scale/shift
//   L4: KNN via fp16-split MFMA (S = QhXh + QhXl + QlXh), per-segment top-16
//   L5: exact 4-way merge of segment partials -> NN
//   L6: gather + BN + ReLU + max over K (4 queries/block, cloud-grouped)

#define TD_B   16
#define TD_P   4096
#define TD_S   1024
#define TD_K   16
#define TD_INF 256
#define TD_OUTF 512

typedef __attribute__((ext_vector_type(8))) _Float16 half8;
typedef __attribute__((ext_vector_type(4))) float    f32x4;
typedef __attribute__((ext_vector_type(2))) float    v2f;

__device__ __forceinline__ unsigned short f2bf(float x) {
    unsigned u = __float_as_uint(x);
    unsigned r = (u + 0x7fffu + ((u >> 16) & 1u)) >> 16;   // RNE
    return (unsigned short)r;
}

struct FpsSm {
    float4 p4[TD_P];      // 64 KB: (x,y,z,-) per point, b128 winner read
    int    sel[TD_S];
    unsigned long long kw[2][8];   // parity-buffered per-wave argmax keys
};
struct GemmSm {
    float As[16 * 260];   // [k][m]
    float Bs[16 * 128];   // [k][n]
};
union SmU {
    FpsSm f; GemmSm g;
    char pad_[84000];     // 1 block/CU: FPS keeps a private CU
};

// One level of a wave64 max-reduce on a u64 key via paired 32-bit DPP +
// 64-bit compare. Result valid in lane 63 after shr 1,2,4,8 + bcast15 + bcast31.
#define TD_DPPSTEP(k, ctl, bc)                                                          \
    {                                                                                   \
        unsigned yh_ = (unsigned)__builtin_amdgcn_update_dpp(                           \
            0, (int)(unsigned)((k) >> 32), (ctl), 0xf, 0xf, (bc));                      \
        unsigned yl_ = (unsigned)__builtin_amdgcn_update_dpp(                           \
            0, (int)(unsigned)(k), (ctl), 0xf, 0xf, (bc));                              \
        unsigned long long y_ = ((unsigned long long)yh_ << 32) | yl_;                  \
        if (y_ > (k)) (k) = y_;                                                         \
    }

__global__ __launch_bounds__(512)
void td_fused(const float* __restrict__ feat, const float* __restrict__ pos,
              const float* __restrict__ W, const float* __restrict__ bias,
              unsigned short* __restrict__ H, float* __restrict__ XX,
              int* __restrict__ FPSI, float* __restrict__ outP,
              float* __restrict__ outB) {
    __shared__ SmU sm;
    const int bx = blockIdx.x;
    const int t  = threadIdx.x;

    if (bx < 16) {
        // ---------------- FPS: one block per cloud, private CU ---------------
        // All 512 threads active (2 waves/SIMD): 8 pts per thread as 4 packed
        // v2f lanes (v_pk_* fp32, contract off => np-bitwise sub,sq,sq,sq,
        // add,add,min per element). key = u64(hi=fp32 bits of min_d, lo=~p):
        // max => largest d, tie -> lowest p. Two waves per SIMD let one wave's
        // DPP-hazard/LDS stalls hide under the other's issue.
        __builtin_amdgcn_s_setprio(2);
        const int b = bx;
        const int w = t >> 6;                 // wave id 0..7
        v2f px[4], py[4], pz[4], md[4];
        int ni0[4], ni1[4];
        float lx, ly, lz;
#pragma unroll
        for (int j = 0; j < 4; ++j) {
            int p0 = j * 1024 + t, p1 = p0 + 512;
            const float* q0 = pos + (size_t)(b * TD_P + p0) * 3;
            const float* q1 = pos + (size_t)(b * TD_P + p1) * 3;
            float x0 = q0[0], y0 = q0[1], z0 = q0[2];
            float x1 = q1[0], y1 = q1[1], z1 = q1[2];
            px[j] = (v2f){x0, x1}; py[j] = (v2f){y0, y1}; pz[j] = (v2f){z0, z1};
            sm.f.p4[p0] = make_float4(x0, y0, z0, 0.0f);
            sm.f.p4[p1] = make_float4(x1, y1, z1, 0.0f);
            md[j] = (v2f){__builtin_inff(), __builtin_inff()};
            ni0[j] = ~p0; ni1[j] = ~p1;
        }
        if (t == 0) sm.f.sel[0] = 0;
        __syncthreads();
        { float4 wp = sm.f.p4[0]; lx = wp.x; ly = wp.y; lz = wp.z; }
        for (int s = 0; s < TD_S - 1; ++s) {
            const int par = s & 1;
            double k[8];
            {
#pragma clang fp contract(off)
                v2f l2x = (v2f){lx, lx}, l2y = (v2f){ly, ly}, l2z = (v2f){lz, lz};
#pragma unroll
                for (int j = 0; j < 4; ++j) {
                    v2f dx = px[j] - l2x;
                    v2f dy = py[j] - l2y;
                    v2f dz = pz[j] - l2z;
                    v2f sx = dx * dx;
                    v2f sy = dy * dy;
                    v2f sz = dz * dz;
                    v2f dd = (sx + sy) + sz;
                    md[j] = __builtin_elementwise_min(md[j], dd);
                    k[2 * j]     = __hiloint2double(__float_as_int(md[j].x), ni0[j]);
                    k[2 * j + 1] = __hiloint2double(__float_as_int(md[j].y), ni1[j]);
                }
            }
            // in-thread tree (7 v_max_f64)
#pragma unroll
            for (int st = 4; st > 0; st >>= 1)
#pragma unroll
                for (int i = 0; i < st; ++i) k[i] = fmax(k[i], k[i + st]);
            unsigned long long tk = (unsigned long long)__double_as_longlong(k[0]);
            TD_DPPSTEP(tk, 0x111, true)    // row_shr:1
            TD_DPPSTEP(tk, 0x112, true)    // row_shr:2
            TD_DPPSTEP(tk, 0x114, true)    // row_shr:4
            TD_DPPSTEP(tk, 0x118, true)    // row_shr:8
            TD_DPPSTEP(tk, 0x142, false)   // row_bcast:15
            TD_DPPSTEP(tk, 0x143, false)   // row_bcast:31
            if ((t & 63) == 63) sm.f.kw[par][w] = tk;
            __syncthreads();
            {
                // 8 wave keys as 4x double2 (b128 reads), 7-deep fmax tree.
                const double2* kd = (const double2*)sm.f.kw[par];
                double2 v0 = kd[0], v1 = kd[1], v2 = kd[2], v3 = kd[3];
                double a0 = fmax(v0.x, v0.y);
                double a1 = fmax(v1.x, v1.y);
                double a2 = fmax(v2.x, v2.y);
                double a3 = fmax(v3.x, v3.y);
                double g01 = fmax(a0, a1);
                double g23 = fmax(a2, a3);
                double gk  = fmax(g01, g23);
                unsigned idx = ~(unsigned)__double2loint(gk);
                if (t == 0) sm.f.sel[s + 1] = (int)idx;
                float4 wp = sm.f.p4[idx];
                lx = wp.x; ly = wp.y; lz = wp.z;
            }
        }
        __syncthreads();
        for (int s = t; s < TD_S; s += 512) {
            int li = sm.f.sel[s];
            int og = b * TD_S + s;
            float4 wp = sm.f.p4[li];
            outP[og * 3 + 0] = wp.x;
            outP[og * 3 + 1] = wp.y;
            outP[og * 3 + 2] = wp.z;
            outB[og] = (float)b;
            FPSI[og] = b * TD_P + li;   // global row index
        }
    } else if (bx < 16 + 1024) {
        // ---------------- MLP GEMM: 256x128 tile, 512 thr, 8x8 micro ---------
        const int gb = bx - 16;
        const int mb = gb >> 2, nb = gb & 3;
        const int tm = t >> 4, tn = t & 15;
        float acc[8][8];
#pragma unroll
        for (int i = 0; i < 8; ++i)
#pragma unroll
            for (int j = 0; j < 8; ++j) acc[i][j] = 0.0f;
        float* As = sm.g.As;
        float* Bs = sm.g.Bs;
        for (int kc = 0; kc < 16; ++kc) {
#pragma unroll
            for (int p2 = 0; p2 < 2; ++p2) {
                int f4 = t + 512 * p2;
                int r = f4 >> 2, c4 = f4 & 3;
                float4 v = *(const float4*)&feat[(size_t)(mb * 256 + r) * 256 + kc * 16 + c4 * 4];
                As[(c4 * 4 + 0) * 260 + r] = v.x;
                As[(c4 * 4 + 1) * 260 + r] = v.y;
                As[(c4 * 4 + 2) * 260 + r] = v.z;
                As[(c4 * 4 + 3) * 260 + r] = v.w;
            }
            {
                int kk = t >> 5, n4 = t & 31;
                float4 v = *(const float4*)&W[(size_t)(kc * 16 + kk) * 512 + nb * 128 + n4 * 4];
                *(float4*)&Bs[kk * 128 + n4 * 4] = v;
            }
            __syncthreads();
#pragma unroll
            for (int kk = 0; kk < 16; ++kk) {
                float4 a0 = *(float4*)&As[kk * 260 + tm * 8];
                float4 a1 = *(float4*)&As[kk * 260 + tm * 8 + 4];
                float4 b0 = *(float4*)&Bs[kk * 128 + tn * 8];
                float4 b1 = *(float4*)&Bs[kk * 128 + tn * 8 + 4];
                float av[8] = {a0.x, a0.y, a0.z, a0.w, a1.x, a1.y, a1.z, a1.w};
                float bv2[8] = {b0.x, b0.y, b0.z, b0.w, b1.x, b1.y, b1.z, b1.w};
#pragma unroll
                for (int i = 0; i < 8; ++i)
#pragma unroll
                    for (int j = 0; j < 8; ++j)
                        acc[i][j] = fmaf(av[i], bv2[j], acc[i][j]);
            }
            __syncthreads();
        }
        float4 bb0 = *(const float4*)&bias[nb * 128 + tn * 8];
        float4 bb1 = *(const float4*)&bias[nb * 128 + tn * 8 + 4];
        float bsv[8] = {bb0.x, bb0.y, bb0.z, bb0.w, bb1.x, bb1.y, bb1.z, bb1.w};
#pragma unroll
        for (int i = 0; i < 8; ++i) {
            int row = mb * 256 + tm * 8 + i;
            uint4 pk;
            pk.x = (unsigned)f2bf(acc[i][0] + bsv[0]) | ((unsigned)f2bf(acc[i][1] + bsv[1]) << 16);
            pk.y = (unsigned)f2bf(acc[i][2] + bsv[2]) | ((unsigned)f2bf(acc[i][3] + bsv[3]) << 16);
            pk.z = (unsigned)f2bf(acc[i][4] + bsv[4]) | ((unsigned)f2bf(acc[i][5] + bsv[5]) << 16);
            pk.w = (unsigned)f2bf(acc[i][6] + bsv[6]) | ((unsigned)f2bf(acc[i][7] + bsv[7]) << 16);
            *(uint4*)&H[(size_t)row * 512 + nb * 128 + tn * 8] = pk;
        }
    } else {
        // ---------------- xx[i] = ||features_i||^2 ---------------------------
        const int xb = bx - 1040;
        const int w = t >> 6, lane = t & 63;
#pragma unroll
        for (int it = 0; it < 8; ++it) {
            int r = xb * 64 + w * 8 + it;
            float4 v = *(const float4*)&feat[(size_t)r * 256 + lane * 4];
            float s = v.x * v.x + v.y * v.y + v.z * v.z + v.w * v.w;
#pragma unroll
            for (int off = 32; off > 0; off >>= 1) s += __shfl_down(s, off, 64);
            if (lane == 0) XX[r] = s;
        }
    }
}

__global__ __launch_bounds__(256)
void td_stats(const unsigned short* __restrict__ H, float* __restrict__ P1,
              float* __restrict__ P2) {
    const int rb = blockIdx.x, t = threadIdx.x;   // 256 blocks x 256 rows
    float s1a = 0, s2a = 0, s1b = 0, s2b = 0;
    for (int r = 0; r < 256; ++r) {
        const unsigned* hp = (const unsigned*)(H + (size_t)(rb * 256 + r) * 512);
        unsigned u = hp[t];
        float lo = __uint_as_float(u << 16);
        float hi = __uint_as_float(u & 0xffff0000u);
        s1a += lo; s2a = fmaf(lo, lo, s2a);
        s1b += hi; s2b = fmaf(hi, hi, s2b);
    }
    P1[rb * 512 + 2 * t] = s1a; P1[rb * 512 + 2 * t + 1] = s1b;
    P2[rb * 512 + 2 * t] = s2a; P2[rb * 512 + 2 * t + 1] = s2b;
}

__global__ __launch_bounds__(512)
void td_bnfin(const float* __restrict__ P1, const float* __restrict__ P2,
              const float* __restrict__ gamma, const float* __restrict__ beta,
              float* __restrict__ SS) {
    const int ch = threadIdx.x;
    float s1 = 0, s2 = 0;
    for (int rb = 0; rb < 256; ++rb) { s1 += P1[rb * 512 + ch]; s2 += P2[rb * 512 + ch]; }
    const float invN = 1.0f / 65536.0f;
    float mu  = s1 * invN;
    float var = s2 * invN - mu * mu;
    float sc  = gamma[ch] * (1.0f / sqrtf(var + 1e-5f));
    float sh  = beta[ch] - mu * sc;
    SS[ch] = sc; SS[512 + ch] = sh;
}

// ---------------------------------------------------------------------------
// KNN via MFMA, fp16 split (hi/lo), 3-pass: S = QhXh + QhXl + QlXh.
// Grid 512 = 16 clouds x 8 q-groups(128q) x 4 candidate segments(1024c).
// Pass-major MFMA order: 4 independent acc chains, dep distance 4.
// ---------------------------------------------------------------------------
__global__ __launch_bounds__(256, 2)
void td_knn2(const float* __restrict__ feat, const float* __restrict__ XX,
             const int* __restrict__ FPSI, float* __restrict__ PD,
             int* __restrict__ PI) {
    __shared__ union {
        _Float16 x[2][32][264];   // [hi/lo][c][k], row pad 8 halfs
        float    dt[128][33];     // aliased after MFMA: d values [q_local][c_local]
    } sm;
    __shared__ float QQs[128];
    __shared__ int   QR[128];

    const int bx = blockIdx.x, t = threadIdx.x;
    const int b = bx & 15, r2 = bx >> 4;          // r2 in [0,32)
    const int qq8 = r2 >> 2, seg = r2 & 3;
    const int cb = b * TD_P;
    const int segbase = cb + seg * 1024;

    if (t < 128) {   // query rows + norms
        int gr = FPSI[b * TD_S + qq8 * 128 + t];
        QR[t] = gr; QQs[t] = XX[gr];
    }
    __syncthreads();

    const int w = t >> 6, lane = t & 63;
    const int m = lane & 15, quad = lane >> 4;

    // ---- Q fragments into registers (A-op: lane holds Q[m][quad*8+j]) ------
    half8 qh[2][8], ql[2][8];
#pragma unroll
    for (int qs = 0; qs < 2; ++qs) {
        const float* qp = feat + (size_t)QR[w * 32 + qs * 16 + m] * 256;
#pragma unroll
        for (int ks = 0; ks < 8; ++ks) {
            float4 f0 = *(const float4*)(qp + ks * 32 + quad * 8);
            float4 f1 = *(const float4*)(qp + ks * 32 + quad * 8 + 4);
            float fv[8] = {f0.x, f0.y, f0.z, f0.w, f1.x, f1.y, f1.z, f1.w};
            half8 h, l;
#pragma unroll
            for (int j = 0; j < 8; ++j) {
                _Float16 hv = (_Float16)fv[j];
                h[j] = hv;
                l[j] = (_Float16)(fv[j] - (float)hv);
            }
            qh[qs][ks] = h; ql[qs][ks] = l;
        }
    }

    float sd[16]; int si[16];
#pragma unroll
    for (int r = 0; r < 16; ++r) { sd[r] = __builtin_inff(); si[r] = 0x7fffffff; }

    const int xrow = t >> 3, part = t & 7;   // staging mapping

    for (int ct = 0; ct < 32; ++ct) {
        __syncthreads();   // prev selection done reading dt (aliases x)
        // ---- stage 32 candidates x 256 k, fp32 -> fp16 hi/lo ---------------
        {
            const float* xp = feat + (size_t)(segbase + ct * 32 + xrow) * 256 + part * 32;
#pragma unroll
            for (int s2 = 0; s2 < 4; ++s2) {
                float4 f0 = *(const float4*)(xp + s2 * 8);
                float4 f1 = *(const float4*)(xp + s2 * 8 + 4);
                float fv[8] = {f0.x, f0.y, f0.z, f0.w, f1.x, f1.y, f1.z, f1.w};
                half8 h, l;
#pragma unroll
                for (int j = 0; j < 8; ++j) {
                    _Float16 hv = (_Float16)fv[j];
                    h[j] = hv;
                    l[j] = (_Float16)(fv[j] - (float)hv);
                }
                *(half8*)&sm.x[0][xrow][part * 32 + s2 * 8] = h;
                *(half8*)&sm.x[1][xrow][part * 32 + s2 * 8] = l;
            }
        }
        __syncthreads();
        // ---- MFMA: pass-major, 4 independent acc chains --------------------
        f32x4 acc[2][2];
        acc[0][0] = (f32x4)0.0f; acc[0][1] = (f32x4)0.0f;
        acc[1][0] = (f32x4)0.0f; acc[1][1] = (f32x4)0.0f;
#pragma unroll
        for (int ks = 0; ks < 8; ++ks) {
            half8 xh0 = *(half8*)&sm.x[0][m][ks * 32 + quad * 8];
            half8 xl0 = *(half8*)&sm.x[1][m][ks * 32 + quad * 8];
            half8 xh1 = *(half8*)&sm.x[0][16 + m][ks * 32 + quad * 8];
            half8 xl1 = *(half8*)&sm.x[1][16 + m][ks * 32 + quad * 8];
            acc[0][0] = __builtin_amdgcn_mfma_f32_16x16x32_f16(ql[0][ks], xh0, acc[0][0], 0, 0, 0);
            acc[0][1] = __builtin_amdgcn_mfma_f32_16x16x32_f16(ql[0][ks], xh1, acc[0][1], 0, 0, 0);
            acc[1][0] = __builtin_amdgcn_mfma_f32_16x16x32_f16(ql[1][ks], xh0, acc[1][0], 0, 0, 0);
            acc[1][1] = __builtin_amdgcn_mfma_f32_16x16x32_f16(ql[1][ks], xh1, acc[1][1], 0, 0, 0);
            acc[0][0] = __builtin_amdgcn_mfma_f32_16x16x32_f16(qh[0][ks], xl0, acc[0][0], 0, 0, 0);
            acc[0][1] = __builtin_amdgcn_mfma_f32_16x16x32_f16(qh[0][ks], xl1, acc[0][1], 0, 0, 0);
            acc[1][0] = __builtin_amdgcn_mfma_f32_16x16x32_f16(qh[1][ks], xl0, acc[1][0], 0, 0, 0);
            acc[1][1] = __builtin_amdgcn_mfma_f32_16x16x32_f16(qh[1][ks], xl1, acc[1][1], 0, 0, 0);
            acc[0][0] = __builtin_amdgcn_mfma_f32_16x16x32_f16(qh[0][ks], xh0, acc[0][0], 0, 0, 0);
            acc[0][1] = __builtin_amdgcn_mfma_f32_16x16x32_f16(qh[0][ks], xh1, acc[0][1], 0, 0, 0);
            acc[1][0] = __builtin_amdgcn_mfma_f32_16x16x32_f16(qh[1][ks], xh0, acc[1][0], 0, 0, 0);
            acc[1][1] = __builtin_amdgcn_mfma_f32_16x16x32_f16(qh[1][ks], xh1, acc[1][1], 0, 0, 0);
        }
        __syncthreads();   // all waves done reading x; safe to alias as dt
        // ---- epilogue: d = (qq - 2S) + xx, dump to dt ----------------------
        {
            float xx0 = XX[segbase + ct * 32 + m];
            float xx1 = XX[segbase + ct * 32 + 16 + m];
#pragma unroll
            for (int qs = 0; qs < 2; ++qs) {
                int qb = w * 32 + qs * 16 + quad * 4;
#pragma unroll
                for (int reg = 0; reg < 4; ++reg) {
                    float qq = QQs[qb + reg];
                    sm.dt[qb + reg][m]      = (qq - 2.0f * acc[qs][0][reg]) + xx0;
                    sm.dt[qb + reg][16 + m] = (qq - 2.0f * acc[qs][1][reg]) + xx1;
                }
            }
        }
        __syncthreads();
        // ---- selection: thread t (<128) owns query t, scans 32 candidates --
        if (t < 128) {
            const int ibase = segbase + ct * 32;
            for (int j = 0; j < 32; ++j) {
                float d = sm.dt[t][j];
                if (d < sd[15]) {
                    sd[15] = d; si[15] = ibase + j;   // ascending idx => strict < ok
#pragma unroll
                    for (int r = 15; r > 0; --r) {
                        if (sd[r] < sd[r - 1]) {
                            float td2 = sd[r]; sd[r] = sd[r - 1]; sd[r - 1] = td2;
                            int ti = si[r]; si[r] = si[r - 1]; si[r - 1] = ti;
                        }
                    }
                }
            }
        }
    }
    // ---- write sorted per-segment partial top-16 ---------------------------
    if (t < 128) {
        size_t o = ((size_t)(b * TD_S + qq8 * 128 + t)) * 64 + seg * 16;
#pragma unroll
        for (int r = 0; r < 16; ++r) { PD[o + r] = sd[r]; PI[o + r] = si[r]; }
    }
}

// Exact 4-way merge of sorted segment partials -> final top-16 per query.
__global__ __launch_bounds__(64)
void td_merge(const float* __restrict__ PD, const int* __restrict__ PI,
              int* __restrict__ NN) {
    __shared__ float ld_[64][65];
    __shared__ int   li_[64][65];
    const int bx = blockIdx.x, t = threadIdx.x;
    for (int j = 0; j < 64; ++j) {
        ld_[j][t] = PD[(size_t)bx * 4096 + j * 64 + t];
        li_[j][t] = PI[(size_t)bx * 4096 + j * 64 + t];
    }
    __syncthreads();
    int p[4] = {0, 0, 0, 0};
    int og = (bx * 64 + t) * TD_K;
    for (int r = 0; r < 16; ++r) {
        float bd = __builtin_inff(); int bi = 0x7fffffff; int bs = 0;
#pragma unroll
        for (int s = 0; s < 4; ++s) {
            if (p[s] < 16) {
                float d = ld_[t][s * 16 + p[s]];
                int   i = li_[t][s * 16 + p[s]];
                if (d < bd || (d == bd && i < bi)) { bd = d; bi = i; bs = s; }
            }
        }
        p[bs]++;
        NN[og + r] = bi;
    }
}

// 4 queries per block; cloud-grouped swizzle for L2 locality on H rows.
__global__ __launch_bounds__(256)
void td_maxpool(const unsigned short* __restrict__ H, const int* __restrict__ NN,
                const float* __restrict__ SS, float* __restrict__ outF) {
    __shared__ int nbr[64];
    const int bx = blockIdx.x, t = threadIdx.x;
    const int cloud = bx & 15, blk = bx >> 4;       // 256 blocks per cloud
    const int qbase = cloud * 1024 + blk * 4;
    if (t < 64) nbr[t] = NN[(size_t)qbase * 16 + t];
    __syncthreads();
    float sc0 = SS[2 * t], sc1 = SS[2 * t + 1];
    float sh0 = SS[512 + 2 * t], sh1 = SS[512 + 2 * t + 1];
#pragma unroll
    for (int qi = 0; qi < 4; ++qi) {
        float m0 = 0.0f, m1 = 0.0f;   // relu floor: max_k relu(v) = max(0, max_k v)
#pragma unroll
        for (int k = 0; k < 16; ++k) {
            int row = nbr[qi * 16 + k];
            unsigned u = ((const unsigned*)(H + (size_t)row * 512))[t];
            float lo = __uint_as_float(u << 16);
            float hi = __uint_as_float(u & 0xffff0000u);
            m0 = fmaxf(m0, fmaf(sc0, lo, sh0));
            m1 = fmaxf(m1, fmaf(sc1, hi, sh1));
        }
        float2 o; o.x = m0; o.y = m1;
        *(float2*)&outF[(size_t)(qbase + qi) * 512 + 2 * t] = o;
    }
}

extern "C" void kernel_launch(void* const* d_in, const int* in_sizes, int n_in,
                              void* d_out, int out_size, void* d_ws, size_t ws_size,
                              hipStream_t stream) {
    const float* feat  = (const float*)d_in[0];
    const float* pos   = (const float*)d_in[1];
    // d_in[2] = batch (int32): unused, value is row/P by construction
    const float* W     = (const float*)d_in[3];
    const float* bias  = (const float*)d_in[4];
    const float* gamma = (const float*)d_in[5];
    const float* beta  = (const float*)d_in[6];

    char* ws = (char*)d_ws;
    unsigned short* H = (unsigned short*)ws;            // 67,108,864 B (bf16 h)
    float* XX  = (float*)(ws + 67108864);               //    262,144 B
    int*   FPSI= (int*)  (ws + 67371008);               //     65,536 B
    int*   NN  = (int*)  (ws + 67436544);               //  1,048,576 B
    float* P1  = (float*)(ws + 68485120);               //    524,288 B used
    float* P2  = (float*)(ws + 69533696);               //    524,288 B used
    float* SS  = (float*)(ws + 70582272);               //      4,096 B
    float* PD  = (float*)(ws + 70586368);               //  4,194,304 B
    int*   PI  = (int*)  (ws + 74780672);               //  4,194,304 B

    float* outF = (float*)d_out;
    float* outP = outF + (size_t)TD_B * TD_S * TD_OUTF;   // 8,388,608
    float* outB = outP + (size_t)TD_B * TD_S * 3;         // +49,152

    td_fused  <<<2064, 512, 0, stream>>>(feat, pos, W, bias, H, XX, FPSI, outP, outB);
    td_stats  <<<256, 256, 0, stream>>>(H, P1, P2);
    td_bnfin  <<<1, 512, 0, stream>>>(P1, P2, gamma, beta, SS);
    td_knn2   <<<512, 256, 0, stream>>>(feat, XX, FPSI, PD, PI);
    td_merge  <<<256, 64, 0, stream>>>(PD, PI, NN);
    td_maxpool<<<TD_B * 256, 256, 0, stream>>>(H, NN, SS, outF);
}